// Round 11
// baseline (371.762 us; speedup 1.0000x reference)
//
#include <hip/hip_runtime.h>
#include <math.h>

#define B_SZ 8
#define SEQ  4096
#define DM   64
#define DI   128
#define NH   2
#define HD   64
#define DS   128
#define DIP  514
#define XW   384           // zxb width: xBC only (z computed in k_fused, dt in DT)
#define CD   384
#define QC   64
#define NC   64
#define NR   (B_SZ*SEQ)
#define WPAD 576

typedef __attribute__((ext_vector_type(8))) short bf16x8;
typedef __attribute__((ext_vector_type(4))) float f32x4;

__device__ __forceinline__ unsigned short f2bf(float f) {
    union { float f; unsigned int u; } x; x.f = f;
    unsigned int r = x.u + 0x7fffu + ((x.u >> 16) & 1u);
    return (unsigned short)(r >> 16);
}
__device__ __forceinline__ float bf2f(unsigned short h) {
    union { unsigned int u; float f; } x; x.u = ((unsigned int)h) << 16;
    return x.f;
}
// A/B-operand frag: lane holds M[r0+(lane&15)][k0 + (lane>>4)*8 + j], row-major [m][k]
__device__ __forceinline__ bf16x8 fragld(const unsigned short* base, int r0, int k0, int ld) {
    int l = threadIdx.x & 63;
    return *(const bf16x8*)(base + (ptrdiff_t)(r0 + (l & 15)) * ld + k0 + (l >> 4) * 8);
}

// ---------------- weight pre-conversion (once per launch) ----------------
__global__ __launch_bounds__(256) void k_wcvt(const float* __restrict__ in_w,
                                              const float* __restrict__ out_w,
                                              unsigned short* __restrict__ Wb,
                                              unsigned short* __restrict__ OWb) {
    int idx = blockIdx.x * 256 + threadIdx.x;
    if (idx < 4 * WPAD * 64) {
        int l = idx / (WPAD * 64), r = idx % (WPAD * 64);
        int n = r >> 6, k = r & 63;
        float v = (n < DIP) ? in_w[(size_t)l * DIP * 64 + (size_t)n * 64 + k] : 0.f;
        Wb[idx] = f2bf(v);
    }
    if (idx < 4 * 64 * 128) OWb[idx] = f2bf(out_w[idx]);
}

// ---------------- residual stream f32 -> bf16 (layer 0 only) ----------------
__global__ __launch_bounds__(256) void k_xcvt(const float* __restrict__ X,
                                              unsigned short* __restrict__ Xb) {
    int idx = (blockIdx.x * 256 + threadIdx.x) * 4;
    float4 v = *(const float4*)(X + idx);
    uint2 p;
    p.x = f2bf(v.x) | ((unsigned int)f2bf(v.y) << 16);
    p.y = f2bf(v.z) | ((unsigned int)f2bf(v.w) << 16);
    *(uint2*)(Xb + idx) = p;
}

// ---------------- in_proj (xBC + dt only): LDS-free MFMA ----------------
__global__ __launch_bounds__(256) void k_inproj(const unsigned short* __restrict__ Xb,
                                                const unsigned short* __restrict__ Wb,
                                                unsigned short* __restrict__ ZXb,
                                                float* __restrict__ DT) {
    int m0 = blockIdx.x * 256;
    int ny = blockIdx.y;               // 0..5: xBC cols; 6: dt
    int tid = threadIdx.x;
    int wid = tid >> 6, lane = tid & 63;
    int q4 = lane >> 4, c16 = lane & 15;
    int mb = m0 + wid * 64;
    bf16x8 af[4][2];
#pragma unroll
    for (int mt = 0; mt < 4; mt++)
#pragma unroll
        for (int ks = 0; ks < 2; ks++)
            af[mt][ks] = *(const bf16x8*)(Xb + (size_t)(mb + mt * 16 + c16) * 64 + ks * 32 + q4 * 8);
    if (ny < 6) {
#pragma unroll
        for (int nt = 0; nt < 4; nt++) {
            bf16x8 bf[2];
#pragma unroll
            for (int ks = 0; ks < 2; ks++)
                bf[ks] = *(const bf16x8*)(Wb + (size_t)(128 + ny * 64 + nt * 16 + c16) * 64 + ks * 32 + q4 * 8);
#pragma unroll
            for (int mt = 0; mt < 4; mt++) {
                f32x4 acc = {0.f, 0.f, 0.f, 0.f};
                acc = __builtin_amdgcn_mfma_f32_16x16x32_bf16(af[mt][0], bf[0], acc, 0, 0, 0);
                acc = __builtin_amdgcn_mfma_f32_16x16x32_bf16(af[mt][1], bf[1], acc, 0, 0, 0);
#pragma unroll
                for (int rr = 0; rr < 4; rr++) {
                    float v = acc[rr];
                    float vn = __shfl_xor(v, 1);
                    if (!(lane & 1)) {
                        unsigned int pk = f2bf(v) | ((unsigned int)f2bf(vn) << 16);
                        *(unsigned int*)(ZXb + (size_t)(mb + mt * 16 + q4 * 4 + rr) * XW + ny * 64 + nt * 16 + c16) = pk;
                    }
                }
            }
        }
    } else {
        bf16x8 bf[2];
#pragma unroll
        for (int ks = 0; ks < 2; ks++)
            bf[ks] = *(const bf16x8*)(Wb + (size_t)(512 + c16) * 64 + ks * 32 + q4 * 8);
#pragma unroll
        for (int mt = 0; mt < 4; mt++) {
            f32x4 acc = {0.f, 0.f, 0.f, 0.f};
            acc = __builtin_amdgcn_mfma_f32_16x16x32_bf16(af[mt][0], bf[0], acc, 0, 0, 0);
            acc = __builtin_amdgcn_mfma_f32_16x16x32_bf16(af[mt][1], bf[1], acc, 0, 0, 0);
            if (c16 < 2)
#pragma unroll
                for (int rr = 0; rr < 4; rr++)
                    DT[(size_t)(mb + mt * 16 + q4 * 4 + rr) * 2 + c16] = acc[rr];
        }
    }
}

// ---------------- chunk1 (1024 thr): dt/cum, conv+SiLU (4x4 blocks), G, M, Y_intra, SL^T ----------------
__global__ __launch_bounds__(1024, 8) void k_chunk1(
        const unsigned short* __restrict__ ZXb, const float* __restrict__ DT,
        const float* __restrict__ CW, const float* __restrict__ CB,
        const float* __restrict__ dtb, const float* __restrict__ Alog,
        const float* __restrict__ Dv,
        unsigned short* __restrict__ SL, unsigned short* __restrict__ CBuf,
        float* __restrict__ EB,
        float* __restrict__ TB, unsigned short* __restrict__ YBb) {
    __shared__ unsigned short sBt[128][72];
    __shared__ unsigned short sXt[128][72];
    __shared__ unsigned short uBC[2][64][136];
    __shared__ float s_cum[2][64], s_dt[2][64], s_w[2][64];
    unsigned short (*sM)[64][72] = (unsigned short (*)[64][72])&uBC[0][0][0];

    int c = blockIdx.x, b = blockIdx.y;
    size_t rbase = (size_t)b * SEQ + c * QC;
    int tid = threadIdx.x;
    int wid = tid >> 6, lane = tid & 63;
    int q4 = lane >> 4, c16 = lane & 15;

    // Phase A: dt/cumsum (waves 0,1) — ordered vs Phase C by the conv barrier
    if (wid < 2) {
        int h = wid, j = lane;
        float raw = DT[(rbase + j) * 2 + h] + dtb[h];
        float dt = (raw > 20.f) ? raw : log1pf(__expf(raw));
        float A = -__expf(Alog[h]);
        float x = dt * A;
        for (int off = 1; off < 64; off <<= 1) {
            float o = __shfl_up(x, off);
            if (lane >= off) x += o;
        }
        float T = __shfl(x, 63);
        s_dt[h][j] = dt;
        s_cum[h][j] = x;
        s_w[h][j] = __expf(T - x) * dt;
        EB[((size_t)(b * NC + c)) * 128 + h * 64 + j] = __expf(x);
        if (j == 0) TB[(b * 2 + h) * NC + c] = __expf(T);
    }

    // Phase B: conv(4)+bias+SiLU in 4j x 4c register blocks; b64 LDS scatter.
    // j-inner lane mapping: 16-lane groups write consecutive 8B chunks of one LDS row.
    size_t cbbase = ((size_t)(b * NC + c)) * 8192;
    for (int it = tid; it < 16 * 96; it += 1024) {
        int j0 = (it & 15) * 4;          // 0..60
        int cq = it >> 4;                // 0..95
        int cc = cq * 4;
        const unsigned short* zp0 = ZXb + rbase * XW + cc;   // row 0 of this chunk
        float4 wv0 = *(const float4*)(CW + (cc + 0) * 4);
        float4 wv1 = *(const float4*)(CW + (cc + 1) * 4);
        float4 wv2 = *(const float4*)(CW + (cc + 2) * 4);
        float4 wv3 = *(const float4*)(CW + (cc + 3) * 4);
        float out[4][4];
        {
            float b0 = CB[cc], b1 = CB[cc + 1], b2 = CB[cc + 2], b3 = CB[cc + 3];
#pragma unroll
            for (int t = 0; t < 4; t++) {
                out[t][0] = b0; out[t][1] = b1; out[t][2] = b2; out[t][3] = b3;
            }
        }
#pragma unroll
        for (int ri = 0; ri < 7; ri++) {
            int r = j0 - 3 + ri;                 // row within chunk, may be <0 (prev chunk)
            uint2 a = make_uint2(0, 0);
            if (c > 0 || r >= 0) a = *(const uint2*)(zp0 + (ptrdiff_t)r * XW);
            float v0 = bf2f((unsigned short)(a.x & 0xffff));
            float v1 = bf2f((unsigned short)(a.x >> 16));
            float v2 = bf2f((unsigned short)(a.y & 0xffff));
            float v3 = bf2f((unsigned short)(a.y >> 16));
#pragma unroll
            for (int t = 0; t < 4; t++) {
                int k = ri - t;                  // tap index: 0 = oldest (row j-3)
                if (k >= 0 && k < 4) {
                    float w0 = (k == 0) ? wv0.x : (k == 1) ? wv0.y : (k == 2) ? wv0.z : wv0.w;
                    float w1 = (k == 0) ? wv1.x : (k == 1) ? wv1.y : (k == 2) ? wv1.z : wv1.w;
                    float w2 = (k == 0) ? wv2.x : (k == 1) ? wv2.y : (k == 2) ? wv2.z : wv2.w;
                    float w3 = (k == 0) ? wv3.x : (k == 1) ? wv3.y : (k == 2) ? wv3.z : wv3.w;
                    out[t][0] += w0 * v0;
                    out[t][1] += w1 * v1;
                    out[t][2] += w2 * v2;
                    out[t][3] += w3 * v3;
                }
            }
        }
#pragma unroll
        for (int t = 0; t < 4; t++)
#pragma unroll
            for (int u = 0; u < 4; u++) {
                float tt = out[t][u];
                out[t][u] = tt / (1.f + __expf(-tt));
            }
        if (cc < 128) {
#pragma unroll
            for (int u = 0; u < 4; u++) {
                uint2 pk;
                pk.x = f2bf(out[0][u]) | ((unsigned int)f2bf(out[1][u]) << 16);
                pk.y = f2bf(out[2][u]) | ((unsigned int)f2bf(out[3][u]) << 16);
                *(uint2*)&sXt[cc + u][j0] = pk;
            }
        } else if (cc < 256) {
            int s = cc - 128;
#pragma unroll
            for (int u = 0; u < 4; u++) {
                uint2 pk;
                pk.x = f2bf(out[0][u]) | ((unsigned int)f2bf(out[1][u]) << 16);
                pk.y = f2bf(out[2][u]) | ((unsigned int)f2bf(out[3][u]) << 16);
                *(uint2*)&sBt[s + u][j0] = pk;
            }
#pragma unroll
            for (int t = 0; t < 4; t++) {
                uint2 pk;
                pk.x = f2bf(out[t][0]) | ((unsigned int)f2bf(out[t][1]) << 16);
                pk.y = f2bf(out[t][2]) | ((unsigned int)f2bf(out[t][3]) << 16);
                *(uint2*)&uBC[0][j0 + t][s] = pk;
            }
        } else {
            int s = cc - 256;
#pragma unroll
            for (int t = 0; t < 4; t++) {
                uint2 pk;
                pk.x = f2bf(out[t][0]) | ((unsigned int)f2bf(out[t][1]) << 16);
                pk.y = f2bf(out[t][2]) | ((unsigned int)f2bf(out[t][3]) << 16);
                *(uint2*)&uBC[1][j0 + t][s] = pk;
            }
        }
    }
    __syncthreads();

    // Coalesced CBuf export from uBC[1] (one uint4 per thread = 16 KB total)
    {
        int row = tid >> 4, sc = (tid & 15) * 8;
        *(uint4*)(CBuf + cbbase + (size_t)row * 128 + sc) = *(const uint4*)&uBC[1][row][sc];
    }

    // Phase C: G = C.B^T (16 tiles / 16 waves), stage in regs, overlay sM
    f32x4 gacc;
    {
        int it = wid >> 2, jt = wid & 3;
        f32x4 acc = {0.f, 0.f, 0.f, 0.f};
        for (int ks = 0; ks < 4; ks++) {
            bf16x8 a = fragld(&uBC[1][0][0], it * 16, ks * 32, 136);
            bf16x8 bb = fragld(&uBC[0][0][0], jt * 16, ks * 32, 136);
            acc = __builtin_amdgcn_mfma_f32_16x16x32_bf16(a, bb, acc, 0, 0, 0);
        }
        gacc = acc;
    }
    __syncthreads();
    {
        int it = wid >> 2, jt = wid & 3;
        int j = jt * 16 + c16;
        for (int rr = 0; rr < 4; rr++) {
            int i = it * 16 + q4 * 4 + rr;
            float gv = gacc[rr];
            for (int h = 0; h < 2; h++) {
                float m = 0.f;
                if (j <= i) m = gv * __expf(s_cum[h][i] - s_cum[h][j]) * s_dt[h][j];
                sM[h][i][j] = f2bf(m);
            }
        }
    }
    __syncthreads();

    // Phase D1: Y_intra = M_h @ X_h + D*x (32 tiles / 16 waves)
#pragma unroll
    for (int u = 0; u < 2; u++) {
        int idx = wid * 2 + u;
        int h = idx >> 4, tt = idx & 15;
        int it = tt >> 2, pt = tt & 3;
        float dco = Dv[h];
        int pg = h * 64 + pt * 16 + c16;
        f32x4 acc;
        for (int rr = 0; rr < 4; rr++) {
            int i = it * 16 + q4 * 4 + rr;
            acc[rr] = dco * bf2f(sXt[pg][i]);
        }
        for (int ks = 0; ks < 2; ks++) {
            bf16x8 a = fragld(&sM[h][0][0], it * 16, ks * 32, 72);
            bf16x8 bb = fragld(&sXt[0][0], h * 64 + pt * 16, ks * 32, 72);
            acc = __builtin_amdgcn_mfma_f32_16x16x32_bf16(a, bb, acc, 0, 0, 0);
        }
        for (int rr = 0; rr < 4; rr++) {
            int i = it * 16 + q4 * 4 + rr;
            float v = acc[rr];
            float vn = __shfl_xor(v, 1);
            if (!(lane & 1)) {
                unsigned int pk = f2bf(v) | ((unsigned int)f2bf(vn) << 16);
                *(unsigned int*)(YBb + (rbase + i) * DI + pg) = pk;
            }
        }
    }
    // Phase D2: SL^T[p][s] (64 tiles / 16 waves)
    size_t slbase = ((size_t)(b * NC + c)) * 16384;
#pragma unroll
    for (int u = 0; u < 4; u++) {
        int idx = wid * 4 + u;
        int ptl = idx >> 3, st = idx & 7;
        int h = ptl >> 2;
        f32x4 acc = {0.f, 0.f, 0.f, 0.f};
        for (int ks = 0; ks < 2; ks++) {
            int jb = ks * 32 + (lane >> 4) * 8;
            bf16x8 a = fragld(&sXt[0][0], ptl * 16, ks * 32, 72);
            bf16x8 aw;
#pragma unroll
            for (int t = 0; t < 8; t++) aw[t] = (short)f2bf(bf2f((unsigned short)a[t]) * s_w[h][jb + t]);
            bf16x8 bb = fragld(&sBt[0][0], st * 16, ks * 32, 72);
            acc = __builtin_amdgcn_mfma_f32_16x16x32_bf16(aw, bb, acc, 0, 0, 0);
        }
        int s = st * 16 + c16;
        for (int rr = 0; rr < 4; rr++) {
            int p = ptl * 16 + q4 * 4 + rr;
            float vv = acc[rr];
            float vn = __shfl_xor(vv, 1);
            if (!(lane & 1)) {
                unsigned int pk = f2bf(vv) | ((unsigned int)f2bf(vn) << 16);
                *(unsigned int*)(SL + slbase + (size_t)p * 128 + s) = pk;
            }
        }
    }
}

// ---------------- cross-chunk state scan (512 blk x 256 thr, prefetch) ----------------
__global__ __launch_bounds__(256) void k_scan(unsigned short* __restrict__ SL,
                                              const float* __restrict__ TB) {
    int bid = blockIdx.x;
    int b = bid >> 6;
    int ps = (bid & 63) * 256 + threadIdx.x;
    int h = ps >> 13;
    const float* dAp = TB + (b * 2 + h) * NC;
    size_t base = (size_t)(b * NC) * 16384 + ps;
    float hacc = 0.f;
    unsigned short cur = SL[base];
#pragma unroll 4
    for (int cc = 0; cc < NC; cc++) {
        unsigned short nxt = 0;
        if (cc + 1 < NC) nxt = SL[base + (size_t)(cc + 1) * 16384];
        float slv = bf2f(cur);
        SL[base + (size_t)cc * 16384] = f2bf(hacc);
        hacc = hacc * dAp[cc] + slv;
        cur = nxt;
    }
}

// ---------------- fused (1024 thr): z-GEMM + Y_inter + gate + RMSNorm + out_proj + residual ----------------
__global__ __launch_bounds__(1024, 8) void k_fused(
        const unsigned short* __restrict__ SL, const unsigned short* __restrict__ CBuf,
        const float* __restrict__ EB,
        const unsigned short* __restrict__ YBb, const unsigned short* __restrict__ Wzb,
        const float* __restrict__ NW, const unsigned short* __restrict__ OWb,
        unsigned short* __restrict__ Xb, float* __restrict__ OutF, int last) {
    __shared__ __attribute__((aligned(16))) unsigned short sH[128][136];
    __shared__ __attribute__((aligned(16))) unsigned short sE[128][136];
    float* sGf = (float*)&sH[0][0];                                   // [64][132] overlay
    unsigned short (*sG)[136] = (unsigned short (*)[136])&sE[0][0];   // [64][136] overlay

    int c = blockIdx.x, b = blockIdx.y;
    size_t rbase = (size_t)b * SEQ + c * QC;
    int tid = threadIdx.x;
    int wid = tid >> 6, lane = tid & 63;
    size_t base = ((size_t)(b * NC + c)) * 16384;
    for (int u = 0; u < 2; u++) {
        int e = u * 1024 + tid;
        int row = e >> 4, cb8 = (e & 15) * 8;
        *(uint4*)&sH[row][cb8] = *(const uint4*)(SL + base + (size_t)row * 128 + cb8);
    }
    size_t cbbase = ((size_t)(b * NC + c)) * 8192;
    size_t ebase  = ((size_t)(b * NC + c)) * 128;
    {
        int i = tid >> 4, sc = (tid & 15) * 8;
        uint4 cv = *(const uint4*)(CBuf + cbbase + (size_t)i * 128 + sc);
        float e0 = EB[ebase + i], e1 = EB[ebase + 64 + i];
        unsigned int w[4] = {cv.x, cv.y, cv.z, cv.w};
        uint4 o0, o1;
        unsigned int* po0 = &o0.x;
        unsigned int* po1 = &o1.x;
#pragma unroll
        for (int t = 0; t < 4; t++) {
            float lo = bf2f((unsigned short)(w[t] & 0xffff));
            float hi = bf2f((unsigned short)(w[t] >> 16));
            po0[t] = f2bf(lo * e0) | ((unsigned int)f2bf(hi * e0) << 16);
            po1[t] = f2bf(lo * e1) | ((unsigned int)f2bf(hi * e1) << 16);
        }
        *(uint4*)&sE[i][sc] = o0;
        *(uint4*)&sE[64 + i][sc] = o1;
    }
    __syncthreads();
    int q4 = lane >> 4, c16 = lane & 15;

    float yv[2][4];
    int tit[2], tpg[2];
#pragma unroll
    for (int u = 0; u < 2; u++) {
        int idx = wid * 2 + u;                 // 32 tiles / 16 waves
        int h = idx >> 4, tt = idx & 15;
        int it = tt >> 2, pt = tt & 3;
        int pg = h * 64 + pt * 16 + c16;
        f32x4 zacc = {0.f, 0.f, 0.f, 0.f};
        f32x4 acc = {0.f, 0.f, 0.f, 0.f};
#pragma unroll
        for (int ks = 0; ks < 2; ks++) {
            bf16x8 xa = fragld(Xb, (int)rbase + it * 16, ks * 32, 64);
            bf16x8 wz = fragld(Wzb, h * 64 + pt * 16, ks * 32, 64);
            zacc = __builtin_amdgcn_mfma_f32_16x16x32_bf16(xa, wz, zacc, 0, 0, 0);
        }
        for (int ks = 0; ks < 4; ks++) {
            bf16x8 a = fragld(&sE[0][0], h * 64 + it * 16, ks * 32, 136);
            bf16x8 bb = fragld(&sH[0][0], h * 64 + pt * 16, ks * 32, 136);
            acc = __builtin_amdgcn_mfma_f32_16x16x32_bf16(a, bb, acc, 0, 0, 0);
        }
        tit[u] = it; tpg[u] = pg;
        for (int rr = 0; rr < 4; rr++) {
            int i = it * 16 + q4 * 4 + rr;
            float y = acc[rr] + bf2f(YBb[(rbase + i) * DI + pg]);
            float z = zacc[rr];
            yv[u][rr] = y * (z / (1.f + __expf(-z)));
        }
    }
    __syncthreads();
#pragma unroll
    for (int u = 0; u < 2; u++)
        for (int rr = 0; rr < 4; rr++) {
            int i = tit[u] * 16 + q4 * 4 + rr;
            sGf[i * 132 + tpg[u]] = yv[u][rr];
        }
    __syncthreads();
    {
        int row = tid >> 4, part = tid & 15;
        int d0 = part * 8;
        float g[8];
        float ss = 0.f;
        for (int t2 = 0; t2 < 8; t2++) { g[t2] = sGf[row * 132 + d0 + t2]; ss += g[t2] * g[t2]; }
        ss += __shfl_xor(ss, 1);
        ss += __shfl_xor(ss, 2);
        ss += __shfl_xor(ss, 4);
        ss += __shfl_xor(ss, 8);
        float rms = rsqrtf(ss * (1.f / 128.f) + 1e-5f);
        for (int t2 = 0; t2 < 8; t2 += 2) {
            unsigned int pk = f2bf(g[t2] * rms * NW[d0 + t2]) |
                              ((unsigned int)f2bf(g[t2 + 1] * rms * NW[d0 + t2 + 1]) << 16);
            *(unsigned int*)&sG[row][d0 + t2] = pk;
        }
    }
    __syncthreads();
    {
        // out_proj: 16 tiles over 16 waves (mt 0..3 × nt 0..3)
        int mt = wid >> 2, nt = wid & 3;
        f32x4 acc = {0.f, 0.f, 0.f, 0.f};
        for (int ks = 0; ks < 4; ks++) {
            bf16x8 a = fragld(&sG[0][0], mt * 16, ks * 32, 136);
            bf16x8 bb = *(const bf16x8*)(OWb + (size_t)(nt * 16 + c16) * 128 + ks * 32 + q4 * 8);
            acc = __builtin_amdgcn_mfma_f32_16x16x32_bf16(a, bb, acc, 0, 0, 0);
        }
        for (int rr = 0; rr < 4; rr++) {
            int m = mt * 16 + q4 * 4 + rr;
            int n = nt * 16 + c16;
            size_t o = (rbase + m) * DM + n;
            float v = bf2f(Xb[o]) + acc[rr];
            if (last) {
                OutF[o] = v;
            } else {
                float vn = __shfl_xor(v, 1);
                if (!(lane & 1)) {
                    unsigned int pk = f2bf(v) | ((unsigned int)f2bf(vn) << 16);
                    *(unsigned int*)(Xb + o) = pk;
                }
            }
        }
    }
}

extern "C" void kernel_launch(void* const* d_in, const int* in_sizes, int n_in,
                              void* d_out, int out_size, void* d_ws, size_t ws_size,
                              hipStream_t stream) {
    const float* x       = (const float*)d_in[0];
    const float* in_w    = (const float*)d_in[1];
    const float* conv_w  = (const float*)d_in[2];
    const float* conv_b  = (const float*)d_in[3];
    const float* dt_bias = (const float*)d_in[4];
    const float* A_log   = (const float*)d_in[5];
    const float* Dp      = (const float*)d_in[6];
    const float* norm_w  = (const float*)d_in[7];
    const float* out_w   = (const float*)d_in[8];
    float* out = (float*)d_out;
    float* ws  = (float*)d_ws;

    float* dt = ws;                                        // NR*2 f32
    float* tb = dt + (size_t)NR * 2;                       // 1024 f32
    float* eb = tb + 1024;                                 // 8*64*128 f32
    unsigned short* zxb  = (unsigned short*)(eb + (size_t)B_SZ * NC * 128); // NR*384
    unsigned short* ybb  = zxb + (size_t)NR * XW;          // NR*128
    unsigned short* sl   = ybb + (size_t)NR * DI;          // 8*64*16384
    unsigned short* cbuf = sl + (size_t)B_SZ * NC * 16384; // 8*64*8192
    unsigned short* xb   = cbuf + (size_t)B_SZ * NC * 8192;// NR*64
    unsigned short* wb   = xb + (size_t)NR * DM;           // 4*576*64
    unsigned short* owb  = wb + (size_t)4 * WPAD * 64;     // 4*64*128

    k_wcvt<<<(4 * WPAD * 64 + 255) / 256, 256, 0, stream>>>(in_w, out_w, wb, owb);
    k_xcvt<<<NR * DM / 1024, 256, 0, stream>>>(x, xb);

    for (int layer = 0; layer < 4; layer++) {
        k_inproj<<<dim3(NR / 256, 7), 256, 0, stream>>>(xb, wb + (size_t)layer * WPAD * 64, zxb, dt);
        k_chunk1<<<dim3(NC, B_SZ), 1024, 0, stream>>>(zxb, dt,
                conv_w + (size_t)layer * CD * 4, conv_b + (size_t)layer * CD,
                dt_bias + layer * NH, A_log + layer * NH, Dp + layer * NH,
                sl, cbuf, eb, tb, ybb);
        k_scan<<<512, 256, 0, stream>>>(sl, tb);
        k_fused<<<dim3(NC, B_SZ), 1024, 0, stream>>>(sl, cbuf, eb, ybb,
                wb + (size_t)layer * WPAD * 64, norm_w + layer * DI,
                owb + (size_t)layer * 64 * 128, xb, out,
                (layer == 3) ? 1 : 0);
    }
}

// Round 12
// 357.014 us; speedup vs baseline: 1.0413x; 1.0413x over previous
//
#include <hip/hip_runtime.h>
#include <math.h>

#define B_SZ 8
#define SEQ  4096
#define DM   64
#define DI   128
#define NH   2
#define HD   64
#define DS   128
#define DIP  514
#define XW   384           // zxb width: xBC only (z computed in k_fused, dt in DT)
#define CD   384
#define QC   64
#define NC   64
#define NR   (B_SZ*SEQ)
#define WPAD 576

typedef __attribute__((ext_vector_type(8))) short bf16x8;
typedef __attribute__((ext_vector_type(4))) float f32x4;

__device__ __forceinline__ unsigned short f2bf(float f) {
    union { float f; unsigned int u; } x; x.f = f;
    unsigned int r = x.u + 0x7fffu + ((x.u >> 16) & 1u);
    return (unsigned short)(r >> 16);
}
__device__ __forceinline__ float bf2f(unsigned short h) {
    union { unsigned int u; float f; } x; x.u = ((unsigned int)h) << 16;
    return x.f;
}
// A/B-operand frag: lane holds M[r0+(lane&15)][k0 + (lane>>4)*8 + j], row-major [m][k]
__device__ __forceinline__ bf16x8 fragld(const unsigned short* base, int r0, int k0, int ld) {
    int l = threadIdx.x & 63;
    return *(const bf16x8*)(base + (ptrdiff_t)(r0 + (l & 15)) * ld + k0 + (l >> 4) * 8);
}

// ---------------- weight pre-conversion (once per launch) ----------------
__global__ __launch_bounds__(256) void k_wcvt(const float* __restrict__ in_w,
                                              const float* __restrict__ out_w,
                                              unsigned short* __restrict__ Wb,
                                              unsigned short* __restrict__ OWb) {
    int idx = blockIdx.x * 256 + threadIdx.x;
    if (idx < 4 * WPAD * 64) {
        int l = idx / (WPAD * 64), r = idx % (WPAD * 64);
        int n = r >> 6, k = r & 63;
        float v = (n < DIP) ? in_w[(size_t)l * DIP * 64 + (size_t)n * 64 + k] : 0.f;
        Wb[idx] = f2bf(v);
    }
    if (idx < 4 * 64 * 128) OWb[idx] = f2bf(out_w[idx]);
}

// ---------------- residual stream f32 -> bf16 (layer 0 only) ----------------
__global__ __launch_bounds__(256) void k_xcvt(const float* __restrict__ X,
                                              unsigned short* __restrict__ Xb) {
    int idx = (blockIdx.x * 256 + threadIdx.x) * 4;
    float4 v = *(const float4*)(X + idx);
    uint2 p;
    p.x = f2bf(v.x) | ((unsigned int)f2bf(v.y) << 16);
    p.y = f2bf(v.z) | ((unsigned int)f2bf(v.w) << 16);
    *(uint2*)(Xb + idx) = p;
}

// ---------------- in_proj (layer 0 only): LDS-free MFMA ----------------
__global__ __launch_bounds__(256) void k_inproj(const unsigned short* __restrict__ Xb,
                                                const unsigned short* __restrict__ Wb,
                                                unsigned short* __restrict__ ZXb,
                                                float* __restrict__ DT) {
    int m0 = blockIdx.x * 256;
    int ny = blockIdx.y;               // 0..5: xBC cols; 6: dt
    int tid = threadIdx.x;
    int wid = tid >> 6, lane = tid & 63;
    int q4 = lane >> 4, c16 = lane & 15;
    int mb = m0 + wid * 64;
    bf16x8 af[4][2];
#pragma unroll
    for (int mt = 0; mt < 4; mt++)
#pragma unroll
        for (int ks = 0; ks < 2; ks++)
            af[mt][ks] = *(const bf16x8*)(Xb + (size_t)(mb + mt * 16 + c16) * 64 + ks * 32 + q4 * 8);
    if (ny < 6) {
#pragma unroll
        for (int nt = 0; nt < 4; nt++) {
            bf16x8 bf[2];
#pragma unroll
            for (int ks = 0; ks < 2; ks++)
                bf[ks] = *(const bf16x8*)(Wb + (size_t)(128 + ny * 64 + nt * 16 + c16) * 64 + ks * 32 + q4 * 8);
#pragma unroll
            for (int mt = 0; mt < 4; mt++) {
                f32x4 acc = {0.f, 0.f, 0.f, 0.f};
                acc = __builtin_amdgcn_mfma_f32_16x16x32_bf16(af[mt][0], bf[0], acc, 0, 0, 0);
                acc = __builtin_amdgcn_mfma_f32_16x16x32_bf16(af[mt][1], bf[1], acc, 0, 0, 0);
#pragma unroll
                for (int rr = 0; rr < 4; rr++) {
                    float v = acc[rr];
                    float vn = __shfl_xor(v, 1);
                    if (!(lane & 1)) {
                        unsigned int pk = f2bf(v) | ((unsigned int)f2bf(vn) << 16);
                        *(unsigned int*)(ZXb + (size_t)(mb + mt * 16 + q4 * 4 + rr) * XW + ny * 64 + nt * 16 + c16) = pk;
                    }
                }
            }
        }
    } else {
        bf16x8 bf[2];
#pragma unroll
        for (int ks = 0; ks < 2; ks++)
            bf[ks] = *(const bf16x8*)(Wb + (size_t)(512 + c16) * 64 + ks * 32 + q4 * 8);
#pragma unroll
        for (int mt = 0; mt < 4; mt++) {
            f32x4 acc = {0.f, 0.f, 0.f, 0.f};
            acc = __builtin_amdgcn_mfma_f32_16x16x32_bf16(af[mt][0], bf[0], acc, 0, 0, 0);
            acc = __builtin_amdgcn_mfma_f32_16x16x32_bf16(af[mt][1], bf[1], acc, 0, 0, 0);
            if (c16 < 2)
#pragma unroll
                for (int rr = 0; rr < 4; rr++)
                    DT[(size_t)(mb + mt * 16 + q4 * 4 + rr) * 2 + c16] = acc[rr];
        }
    }
}

// ---------------- chunk1 (1024 thr, R10 form): dt/cum, conv+SiLU, G, M, Y_intra, SL^T ----------------
__global__ __launch_bounds__(1024, 8) void k_chunk1(
        const unsigned short* __restrict__ ZXb, const float* __restrict__ DT,
        const float* __restrict__ CW, const float* __restrict__ CB,
        const float* __restrict__ dtb, const float* __restrict__ Alog,
        const float* __restrict__ Dv,
        unsigned short* __restrict__ SL, unsigned short* __restrict__ CBuf,
        float* __restrict__ EB,
        float* __restrict__ TB, unsigned short* __restrict__ YBb) {
    __shared__ unsigned short sBt[128][72];
    __shared__ unsigned short sXt[128][72];
    __shared__ unsigned short uBC[2][64][136];
    __shared__ float s_cum[2][64], s_dt[2][64], s_w[2][64];
    unsigned short (*sM)[64][72] = (unsigned short (*)[64][72])&uBC[0][0][0];

    int c = blockIdx.x, b = blockIdx.y;
    size_t rbase = (size_t)b * SEQ + c * QC;
    int tid = threadIdx.x;
    int wid = tid >> 6, lane = tid & 63;
    int q4 = lane >> 4, c16 = lane & 15;

    // Phase A: dt/cumsum (waves 0,1) — ordered vs Phase C by the conv barrier
    if (wid < 2) {
        int h = wid, j = lane;
        float raw = DT[(rbase + j) * 2 + h] + dtb[h];
        float dt = (raw > 20.f) ? raw : log1pf(__expf(raw));
        float A = -__expf(Alog[h]);
        float x = dt * A;
        for (int off = 1; off < 64; off <<= 1) {
            float o = __shfl_up(x, off);
            if (lane >= off) x += o;
        }
        float T = __shfl(x, 63);
        s_dt[h][j] = dt;
        s_cum[h][j] = x;
        s_w[h][j] = __expf(T - x) * dt;
        EB[((size_t)(b * NC + c)) * 128 + h * 64 + j] = __expf(x);
        if (j == 0) TB[(b * 2 + h) * NC + c] = __expf(T);
    }

    // Phase B: conv(4)+bias+SiLU from global ZXb (width 384); scatter to MFMA layouts
    size_t cbbase = ((size_t)(b * NC + c)) * 8192;
    for (int e = tid; e < 64 * 96; e += 1024) {
        int j = e / 96;
        int q = e - j * 96;
        int cc = q * 4;
        int l = c * QC + j;
        const unsigned short* zp = ZXb + (rbase + j) * XW + cc;
        uint2 a0 = *(const uint2*)zp;
        uint2 a1 = make_uint2(0, 0), a2 = make_uint2(0, 0), a3 = make_uint2(0, 0);
        if (l >= 1) a1 = *(const uint2*)(zp - XW);
        if (l >= 2) a2 = *(const uint2*)(zp - 2 * XW);
        if (l >= 3) a3 = *(const uint2*)(zp - 3 * XW);
        float v[4];
#pragma unroll
        for (int u = 0; u < 4; u++) {
            unsigned int w0 = (u < 2) ? a0.x : a0.y;
            unsigned int w1 = (u < 2) ? a1.x : a1.y;
            unsigned int w2 = (u < 2) ? a2.x : a2.y;
            unsigned int w3 = (u < 2) ? a3.x : a3.y;
            int sh = (u & 1) * 16;
            float r0 = bf2f((unsigned short)(w0 >> sh));
            float r1 = bf2f((unsigned short)(w1 >> sh));
            float r2 = bf2f((unsigned short)(w2 >> sh));
            float r3 = bf2f((unsigned short)(w3 >> sh));
            float4 wv = *(const float4*)(CW + (cc + u) * 4);
            float tt = CB[cc + u] + wv.w * r0 + wv.z * r1 + wv.y * r2 + wv.x * r3;
            v[u] = tt / (1.f + __expf(-tt));
        }
        if (cc < 128) {
#pragma unroll
            for (int u = 0; u < 4; u++) sXt[cc + u][j] = f2bf(v[u]);
        } else if (cc < 256) {
            int s = cc - 128;
            unsigned int p0 = f2bf(v[0]) | ((unsigned int)f2bf(v[1]) << 16);
            unsigned int p1 = f2bf(v[2]) | ((unsigned int)f2bf(v[3]) << 16);
            *(uint2*)&uBC[0][j][s] = make_uint2(p0, p1);
#pragma unroll
            for (int u = 0; u < 4; u++) sBt[s + u][j] = f2bf(v[u]);
        } else {
            int s = cc - 256;
            unsigned int p0 = f2bf(v[0]) | ((unsigned int)f2bf(v[1]) << 16);
            unsigned int p1 = f2bf(v[2]) | ((unsigned int)f2bf(v[3]) << 16);
            *(uint2*)&uBC[1][j][s] = make_uint2(p0, p1);
            *(uint2*)(CBuf + cbbase + (size_t)j * 128 + s) = make_uint2(p0, p1);
        }
    }
    __syncthreads();

    // Phase C: G = C.B^T (16 tiles / 16 waves), stage in regs, overlay sM
    f32x4 gacc;
    {
        int it = wid >> 2, jt = wid & 3;
        f32x4 acc = {0.f, 0.f, 0.f, 0.f};
        for (int ks = 0; ks < 4; ks++) {
            bf16x8 a = fragld(&uBC[1][0][0], it * 16, ks * 32, 136);
            bf16x8 bb = fragld(&uBC[0][0][0], jt * 16, ks * 32, 136);
            acc = __builtin_amdgcn_mfma_f32_16x16x32_bf16(a, bb, acc, 0, 0, 0);
        }
        gacc = acc;
    }
    __syncthreads();
    {
        int it = wid >> 2, jt = wid & 3;
        int j = jt * 16 + c16;
        for (int rr = 0; rr < 4; rr++) {
            int i = it * 16 + q4 * 4 + rr;
            float gv = gacc[rr];
            for (int h = 0; h < 2; h++) {
                float m = 0.f;
                if (j <= i) m = gv * __expf(s_cum[h][i] - s_cum[h][j]) * s_dt[h][j];
                sM[h][i][j] = f2bf(m);
            }
        }
    }
    __syncthreads();

    // Phase D1: Y_intra = M_h @ X_h + D*x (32 tiles / 16 waves)
#pragma unroll
    for (int u = 0; u < 2; u++) {
        int idx = wid * 2 + u;
        int h = idx >> 4, tt = idx & 15;
        int it = tt >> 2, pt = tt & 3;
        float dco = Dv[h];
        int pg = h * 64 + pt * 16 + c16;
        f32x4 acc;
        for (int rr = 0; rr < 4; rr++) {
            int i = it * 16 + q4 * 4 + rr;
            acc[rr] = dco * bf2f(sXt[pg][i]);
        }
        for (int ks = 0; ks < 2; ks++) {
            bf16x8 a = fragld(&sM[h][0][0], it * 16, ks * 32, 72);
            bf16x8 bb = fragld(&sXt[0][0], h * 64 + pt * 16, ks * 32, 72);
            acc = __builtin_amdgcn_mfma_f32_16x16x32_bf16(a, bb, acc, 0, 0, 0);
        }
        for (int rr = 0; rr < 4; rr++) {
            int i = it * 16 + q4 * 4 + rr;
            float v = acc[rr];
            float vn = __shfl_xor(v, 1);
            if (!(lane & 1)) {
                unsigned int pk = f2bf(v) | ((unsigned int)f2bf(vn) << 16);
                *(unsigned int*)(YBb + (rbase + i) * DI + pg) = pk;
            }
        }
    }
    // Phase D2: SL^T[p][s] (64 tiles / 16 waves)
    size_t slbase = ((size_t)(b * NC + c)) * 16384;
#pragma unroll
    for (int u = 0; u < 4; u++) {
        int idx = wid * 4 + u;
        int ptl = idx >> 3, st = idx & 7;
        int h = ptl >> 2;
        f32x4 acc = {0.f, 0.f, 0.f, 0.f};
        for (int ks = 0; ks < 2; ks++) {
            int jb = ks * 32 + (lane >> 4) * 8;
            bf16x8 a = fragld(&sXt[0][0], ptl * 16, ks * 32, 72);
            bf16x8 aw;
#pragma unroll
            for (int t = 0; t < 8; t++) aw[t] = (short)f2bf(bf2f((unsigned short)a[t]) * s_w[h][jb + t]);
            bf16x8 bb = fragld(&sBt[0][0], st * 16, ks * 32, 72);
            acc = __builtin_amdgcn_mfma_f32_16x16x32_bf16(aw, bb, acc, 0, 0, 0);
        }
        int s = st * 16 + c16;
        for (int rr = 0; rr < 4; rr++) {
            int p = ptl * 16 + q4 * 4 + rr;
            float vv = acc[rr];
            float vn = __shfl_xor(vv, 1);
            if (!(lane & 1)) {
                unsigned int pk = f2bf(vv) | ((unsigned int)f2bf(vn) << 16);
                *(unsigned int*)(SL + slbase + (size_t)p * 128 + s) = pk;
            }
        }
    }
}

// ---------------- cross-chunk state scan (R5/R10 form: 512 blk x 256 thr) ----------------
__global__ __launch_bounds__(256) void k_scan(unsigned short* __restrict__ SL,
                                              const float* __restrict__ TB) {
    int bid = blockIdx.x;
    int b = bid >> 6;
    int ps = (bid & 63) * 256 + threadIdx.x;
    int h = ps >> 13;
    const float* dAp = TB + (b * 2 + h) * NC;
    size_t base = (size_t)(b * NC) * 16384 + ps;
    float hacc = 0.f;
#pragma unroll 8
    for (int cc = 0; cc < NC; cc++) {
        size_t idx = base + (size_t)cc * 16384;
        float slv = bf2f(SL[idx]);
        SL[idx] = f2bf(hacc);
        hacc = hacc * dAp[cc] + slv;
    }
}

// ---------------- fused (1024 thr): z-GEMM + Y_inter + gate + RMSNorm + out_proj + residual
//                  + next-layer in_proj (row-local, from LDS) ----------------
__global__ __launch_bounds__(1024, 8) void k_fused(
        const unsigned short* __restrict__ SL, const unsigned short* __restrict__ CBuf,
        const float* __restrict__ EB,
        const unsigned short* __restrict__ YBb, const unsigned short* __restrict__ Wzb,
        const float* __restrict__ NW, const unsigned short* __restrict__ OWb,
        unsigned short* __restrict__ Xb, float* __restrict__ OutF,
        const unsigned short* __restrict__ WbN,      // next layer's in_proj weights (bf16)
        unsigned short* __restrict__ ZXbO,           // next layer's xBC buffer
        float* __restrict__ DTO,                     // next layer's dt buffer
        int last) {
    __shared__ __attribute__((aligned(16))) unsigned short sH[128][136];
    __shared__ __attribute__((aligned(16))) unsigned short sE[128][136];
    float* sGf = (float*)&sH[0][0];                                   // [64][132] overlay (dead after RMS)
    unsigned short (*sG)[136] = (unsigned short (*)[136])&sE[0][0];   // [64][136] overlay
    unsigned short (*sX2)[72] = (unsigned short (*)[72])&sH[0][0];    // [64][72] overlay (written in out_proj)

    int c = blockIdx.x, b = blockIdx.y;
    size_t rbase = (size_t)b * SEQ + c * QC;
    int tid = threadIdx.x;
    int wid = tid >> 6, lane = tid & 63;
    size_t base = ((size_t)(b * NC + c)) * 16384;
    for (int u = 0; u < 2; u++) {
        int e = u * 1024 + tid;
        int row = e >> 4, cb8 = (e & 15) * 8;
        *(uint4*)&sH[row][cb8] = *(const uint4*)(SL + base + (size_t)row * 128 + cb8);
    }
    size_t cbbase = ((size_t)(b * NC + c)) * 8192;
    size_t ebase  = ((size_t)(b * NC + c)) * 128;
    {
        int i = tid >> 4, sc = (tid & 15) * 8;
        uint4 cv = *(const uint4*)(CBuf + cbbase + (size_t)i * 128 + sc);
        float e0 = EB[ebase + i], e1 = EB[ebase + 64 + i];
        unsigned int w[4] = {cv.x, cv.y, cv.z, cv.w};
        uint4 o0, o1;
        unsigned int* po0 = &o0.x;
        unsigned int* po1 = &o1.x;
#pragma unroll
        for (int t = 0; t < 4; t++) {
            float lo = bf2f((unsigned short)(w[t] & 0xffff));
            float hi = bf2f((unsigned short)(w[t] >> 16));
            po0[t] = f2bf(lo * e0) | ((unsigned int)f2bf(hi * e0) << 16);
            po1[t] = f2bf(lo * e1) | ((unsigned int)f2bf(hi * e1) << 16);
        }
        *(uint4*)&sE[i][sc] = o0;
        *(uint4*)&sE[64 + i][sc] = o1;
    }
    __syncthreads();
    int q4 = lane >> 4, c16 = lane & 15;

    float yv[2][4];
    int tit[2], tpg[2];
#pragma unroll
    for (int u = 0; u < 2; u++) {
        int idx = wid * 2 + u;                 // 32 tiles / 16 waves
        int h = idx >> 4, tt = idx & 15;
        int it = tt >> 2, pt = tt & 3;
        int pg = h * 64 + pt * 16 + c16;
        f32x4 zacc = {0.f, 0.f, 0.f, 0.f};
        f32x4 acc = {0.f, 0.f, 0.f, 0.f};
#pragma unroll
        for (int ks = 0; ks < 2; ks++) {
            bf16x8 xa = fragld(Xb, (int)rbase + it * 16, ks * 32, 64);
            bf16x8 wz = fragld(Wzb, h * 64 + pt * 16, ks * 32, 64);
            zacc = __builtin_amdgcn_mfma_f32_16x16x32_bf16(xa, wz, zacc, 0, 0, 0);
        }
        for (int ks = 0; ks < 4; ks++) {
            bf16x8 a = fragld(&sE[0][0], h * 64 + it * 16, ks * 32, 136);
            bf16x8 bb = fragld(&sH[0][0], h * 64 + pt * 16, ks * 32, 136);
            acc = __builtin_amdgcn_mfma_f32_16x16x32_bf16(a, bb, acc, 0, 0, 0);
        }
        tit[u] = it; tpg[u] = pg;
        for (int rr = 0; rr < 4; rr++) {
            int i = it * 16 + q4 * 4 + rr;
            float y = acc[rr] + bf2f(YBb[(rbase + i) * DI + pg]);
            float z = zacc[rr];
            yv[u][rr] = y * (z / (1.f + __expf(-z)));
        }
    }
    __syncthreads();
#pragma unroll
    for (int u = 0; u < 2; u++)
        for (int rr = 0; rr < 4; rr++) {
            int i = tit[u] * 16 + q4 * 4 + rr;
            sGf[i * 132 + tpg[u]] = yv[u][rr];
        }
    __syncthreads();
    {
        int row = tid >> 4, part = tid & 15;
        int d0 = part * 8;
        float g[8];
        float ss = 0.f;
        for (int t2 = 0; t2 < 8; t2++) { g[t2] = sGf[row * 132 + d0 + t2]; ss += g[t2] * g[t2]; }
        ss += __shfl_xor(ss, 1);
        ss += __shfl_xor(ss, 2);
        ss += __shfl_xor(ss, 4);
        ss += __shfl_xor(ss, 8);
        float rms = rsqrtf(ss * (1.f / 128.f) + 1e-5f);
        for (int t2 = 0; t2 < 8; t2 += 2) {
            unsigned int pk = f2bf(g[t2] * rms * NW[d0 + t2]) |
                              ((unsigned int)f2bf(g[t2 + 1] * rms * NW[d0 + t2 + 1]) << 16);
            *(unsigned int*)&sG[row][d0 + t2] = pk;
        }
    }
    __syncthreads();
    {
        // out_proj: 16 tiles over 16 waves (mt 0..3 × nt 0..3); also stage new-x into sX2
        int mt = wid >> 2, nt = wid & 3;
        f32x4 acc = {0.f, 0.f, 0.f, 0.f};
        for (int ks = 0; ks < 4; ks++) {
            bf16x8 a = fragld(&sG[0][0], mt * 16, ks * 32, 136);
            bf16x8 bb = *(const bf16x8*)(OWb + (size_t)(nt * 16 + c16) * 128 + ks * 32 + q4 * 8);
            acc = __builtin_amdgcn_mfma_f32_16x16x32_bf16(a, bb, acc, 0, 0, 0);
        }
        for (int rr = 0; rr < 4; rr++) {
            int m = mt * 16 + q4 * 4 + rr;
            int n = nt * 16 + c16;
            size_t o = (rbase + m) * DM + n;
            float v = bf2f(Xb[o]) + acc[rr];
            if (last) {
                OutF[o] = v;
            } else {
                unsigned short vb = f2bf(v);
                sX2[m][n] = vb;
                float vn = __shfl_xor(v, 1);
                if (!(lane & 1)) {
                    unsigned int pk = (unsigned int)vb | ((unsigned int)f2bf(vn) << 16);
                    *(unsigned int*)(Xb + o) = pk;
                }
            }
        }
    }
    if (!last) {
        __syncthreads();
        // next-layer in_proj for rows rbase..rbase+63: 100 tile jobs over 16 waves
        // t<96: xBC tile (mt = t&3, n0 = (t>>2)*16); t in [96,100): dt tile (mt = t-96)
        for (int t = wid; t < 100; t += 16) {
            int mt2, n0;
            int isdt = (t >= 96);
            if (!isdt) { mt2 = t & 3; n0 = (t >> 2) * 16; }
            else       { mt2 = t - 96; n0 = 0; }
            bf16x8 a0 = fragld(&sX2[0][0], mt2 * 16, 0, 72);
            bf16x8 a1 = fragld(&sX2[0][0], mt2 * 16, 32, 72);
            const unsigned short* wrow = isdt ? (WbN + (size_t)(512 + c16) * 64)
                                              : (WbN + (size_t)(128 + n0 + c16) * 64);
            bf16x8 b0 = *(const bf16x8*)(wrow + q4 * 8);
            bf16x8 b1 = *(const bf16x8*)(wrow + 32 + q4 * 8);
            f32x4 acc = {0.f, 0.f, 0.f, 0.f};
            acc = __builtin_amdgcn_mfma_f32_16x16x32_bf16(a0, b0, acc, 0, 0, 0);
            acc = __builtin_amdgcn_mfma_f32_16x16x32_bf16(a1, b1, acc, 0, 0, 0);
            if (!isdt) {
#pragma unroll
                for (int rr = 0; rr < 4; rr++) {
                    float v = acc[rr];
                    float vn = __shfl_xor(v, 1);
                    if (!(lane & 1)) {
                        unsigned int pk = f2bf(v) | ((unsigned int)f2bf(vn) << 16);
                        *(unsigned int*)(ZXbO + (rbase + mt2 * 16 + q4 * 4 + rr) * XW + n0 + c16) = pk;
                    }
                }
            } else {
                if (c16 < 2)
#pragma unroll
                    for (int rr = 0; rr < 4; rr++)
                        DTO[(rbase + mt2 * 16 + q4 * 4 + rr) * 2 + c16] = acc[rr];
            }
        }
    }
}

extern "C" void kernel_launch(void* const* d_in, const int* in_sizes, int n_in,
                              void* d_out, int out_size, void* d_ws, size_t ws_size,
                              hipStream_t stream) {
    const float* x       = (const float*)d_in[0];
    const float* in_w    = (const float*)d_in[1];
    const float* conv_w  = (const float*)d_in[2];
    const float* conv_b  = (const float*)d_in[3];
    const float* dt_bias = (const float*)d_in[4];
    const float* A_log   = (const float*)d_in[5];
    const float* Dp      = (const float*)d_in[6];
    const float* norm_w  = (const float*)d_in[7];
    const float* out_w   = (const float*)d_in[8];
    float* out = (float*)d_out;
    float* ws  = (float*)d_ws;

    float* dt = ws;                                        // NR*2 f32
    float* tb = dt + (size_t)NR * 2;                       // 1024 f32
    float* eb = tb + 1024;                                 // 8*64*128 f32
    unsigned short* zxb  = (unsigned short*)(eb + (size_t)B_SZ * NC * 128); // NR*384
    unsigned short* ybb  = zxb + (size_t)NR * XW;          // NR*128
    unsigned short* sl   = ybb + (size_t)NR * DI;          // 8*64*16384
    unsigned short* cbuf = sl + (size_t)B_SZ * NC * 16384; // 8*64*8192
    unsigned short* xb   = cbuf + (size_t)B_SZ * NC * 8192;// NR*64
    unsigned short* wb   = xb + (size_t)NR * DM;           // 4*576*64
    unsigned short* owb  = wb + (size_t)4 * WPAD * 64;     // 4*64*128

    k_wcvt<<<(4 * WPAD * 64 + 255) / 256, 256, 0, stream>>>(in_w, out_w, wb, owb);
    k_xcvt<<<NR * DM / 1024, 256, 0, stream>>>(x, xb);
    k_inproj<<<dim3(NR / 256, 7), 256, 0, stream>>>(xb, wb, zxb, dt);   // layer 0 only

    for (int layer = 0; layer < 4; layer++) {
        int nl = (layer < 3) ? layer + 1 : 3;
        k_chunk1<<<dim3(NC, B_SZ), 1024, 0, stream>>>(zxb, dt,
                conv_w + (size_t)layer * CD * 4, conv_b + (size_t)layer * CD,
                dt_bias + layer * NH, A_log + layer * NH, Dp + layer * NH,
                sl, cbuf, eb, tb, ybb);
        k_scan<<<512, 256, 0, stream>>>(sl, tb);
        k_fused<<<dim3(NC, B_SZ), 1024, 0, stream>>>(sl, cbuf, eb, ybb,
                wb + (size_t)layer * WPAD * 64, norm_w + layer * DI,
                owb + (size_t)layer * 64 * 128, xb, out,
                wb + (size_t)nl * WPAD * 64, zxb, dt,
                (layer == 3) ? 1 : 0);
    }
}

// Round 13
// 350.558 us; speedup vs baseline: 1.0605x; 1.0184x over previous
//
#include <hip/hip_runtime.h>
#include <math.h>

#define B_SZ 8
#define SEQ  4096
#define DM   64
#define DI   128
#define NH   2
#define HD   64
#define DS   128
#define DIP  514
#define XW   384           // zxb width: xBC only (z computed in k_fused, dt in DT)
#define CD   384
#define QC   64
#define NC   64
#define NR   (B_SZ*SEQ)
#define WPAD 576

typedef __attribute__((ext_vector_type(8))) short bf16x8;
typedef __attribute__((ext_vector_type(4))) float f32x4;

__device__ __forceinline__ unsigned short f2bf(float f) {
    union { float f; unsigned int u; } x; x.f = f;
    unsigned int r = x.u + 0x7fffu + ((x.u >> 16) & 1u);
    return (unsigned short)(r >> 16);
}
__device__ __forceinline__ float bf2f(unsigned short h) {
    union { unsigned int u; float f; } x; x.u = ((unsigned int)h) << 16;
    return x.f;
}
// A/B-operand frag: lane holds M[r0+(lane&15)][k0 + (lane>>4)*8 + j], row-major [m][k]
__device__ __forceinline__ bf16x8 fragld(const unsigned short* base, int r0, int k0, int ld) {
    int l = threadIdx.x & 63;
    return *(const bf16x8*)(base + (ptrdiff_t)(r0 + (l & 15)) * ld + k0 + (l >> 4) * 8);
}

// ---------------- weight pre-conversion (once per launch) ----------------
__global__ __launch_bounds__(256) void k_wcvt(const float* __restrict__ in_w,
                                              const float* __restrict__ out_w,
                                              unsigned short* __restrict__ Wb,
                                              unsigned short* __restrict__ OWb) {
    int idx = blockIdx.x * 256 + threadIdx.x;
    if (idx < 4 * WPAD * 64) {
        int l = idx / (WPAD * 64), r = idx % (WPAD * 64);
        int n = r >> 6, k = r & 63;
        float v = (n < DIP) ? in_w[(size_t)l * DIP * 64 + (size_t)n * 64 + k] : 0.f;
        Wb[idx] = f2bf(v);
    }
    if (idx < 4 * 64 * 128) OWb[idx] = f2bf(out_w[idx]);
}

// ---------------- residual stream f32 -> bf16 (layer 0 only) ----------------
__global__ __launch_bounds__(256) void k_xcvt(const float* __restrict__ X,
                                              unsigned short* __restrict__ Xb) {
    int idx = (blockIdx.x * 256 + threadIdx.x) * 4;
    float4 v = *(const float4*)(X + idx);
    uint2 p;
    p.x = f2bf(v.x) | ((unsigned int)f2bf(v.y) << 16);
    p.y = f2bf(v.z) | ((unsigned int)f2bf(v.w) << 16);
    *(uint2*)(Xb + idx) = p;
}

// ---------------- in_proj (layer 0 only): LDS-free MFMA ----------------
__global__ __launch_bounds__(256) void k_inproj(const unsigned short* __restrict__ Xb,
                                                const unsigned short* __restrict__ Wb,
                                                unsigned short* __restrict__ ZXb,
                                                float* __restrict__ DT) {
    int m0 = blockIdx.x * 256;
    int ny = blockIdx.y;               // 0..5: xBC cols; 6: dt
    int tid = threadIdx.x;
    int wid = tid >> 6, lane = tid & 63;
    int q4 = lane >> 4, c16 = lane & 15;
    int mb = m0 + wid * 64;
    bf16x8 af[4][2];
#pragma unroll
    for (int mt = 0; mt < 4; mt++)
#pragma unroll
        for (int ks = 0; ks < 2; ks++)
            af[mt][ks] = *(const bf16x8*)(Xb + (size_t)(mb + mt * 16 + c16) * 64 + ks * 32 + q4 * 8);
    if (ny < 6) {
#pragma unroll
        for (int nt = 0; nt < 4; nt++) {
            bf16x8 bf[2];
#pragma unroll
            for (int ks = 0; ks < 2; ks++)
                bf[ks] = *(const bf16x8*)(Wb + (size_t)(128 + ny * 64 + nt * 16 + c16) * 64 + ks * 32 + q4 * 8);
#pragma unroll
            for (int mt = 0; mt < 4; mt++) {
                f32x4 acc = {0.f, 0.f, 0.f, 0.f};
                acc = __builtin_amdgcn_mfma_f32_16x16x32_bf16(af[mt][0], bf[0], acc, 0, 0, 0);
                acc = __builtin_amdgcn_mfma_f32_16x16x32_bf16(af[mt][1], bf[1], acc, 0, 0, 0);
#pragma unroll
                for (int rr = 0; rr < 4; rr++) {
                    float v = acc[rr];
                    float vn = __shfl_xor(v, 1);
                    if (!(lane & 1)) {
                        unsigned int pk = f2bf(v) | ((unsigned int)f2bf(vn) << 16);
                        *(unsigned int*)(ZXb + (size_t)(mb + mt * 16 + q4 * 4 + rr) * XW + ny * 64 + nt * 16 + c16) = pk;
                    }
                }
            }
        }
    } else {
        bf16x8 bf[2];
#pragma unroll
        for (int ks = 0; ks < 2; ks++)
            bf[ks] = *(const bf16x8*)(Wb + (size_t)(512 + c16) * 64 + ks * 32 + q4 * 8);
#pragma unroll
        for (int mt = 0; mt < 4; mt++) {
            f32x4 acc = {0.f, 0.f, 0.f, 0.f};
            acc = __builtin_amdgcn_mfma_f32_16x16x32_bf16(af[mt][0], bf[0], acc, 0, 0, 0);
            acc = __builtin_amdgcn_mfma_f32_16x16x32_bf16(af[mt][1], bf[1], acc, 0, 0, 0);
            if (c16 < 2)
#pragma unroll
                for (int rr = 0; rr < 4; rr++)
                    DT[(size_t)(mb + mt * 16 + q4 * 4 + rr) * 2 + c16] = acc[rr];
        }
    }
}

// ---------------- chunk1 (1024 thr): dt/cum, conv+SiLU, G, M, Y_intra(tile-major), SL^T ----------------
__global__ __launch_bounds__(1024, 8) void k_chunk1(
        const unsigned short* __restrict__ ZXb, const float* __restrict__ DT,
        const float* __restrict__ CW, const float* __restrict__ CB,
        const float* __restrict__ dtb, const float* __restrict__ Alog,
        const float* __restrict__ Dv,
        unsigned short* __restrict__ SL, unsigned short* __restrict__ CBuf,
        float* __restrict__ EB,
        float* __restrict__ TB, unsigned short* __restrict__ YBb) {
    __shared__ unsigned short sBt[128][72];
    __shared__ unsigned short sXt[128][72];
    __shared__ unsigned short uBC[2][64][136];
    __shared__ float s_cum[2][64], s_dt[2][64], s_w[2][64];
    unsigned short (*sM)[64][72] = (unsigned short (*)[64][72])&uBC[0][0][0];

    int c = blockIdx.x, b = blockIdx.y;
    size_t rbase = (size_t)b * SEQ + c * QC;
    int tid = threadIdx.x;
    int wid = tid >> 6, lane = tid & 63;
    int q4 = lane >> 4, c16 = lane & 15;

    // Phase A: dt/cumsum (waves 0,1) — ordered vs Phase C by the conv barrier
    if (wid < 2) {
        int h = wid, j = lane;
        float raw = DT[(rbase + j) * 2 + h] + dtb[h];
        float dt = (raw > 20.f) ? raw : log1pf(__expf(raw));
        float A = -__expf(Alog[h]);
        float x = dt * A;
        for (int off = 1; off < 64; off <<= 1) {
            float o = __shfl_up(x, off);
            if (lane >= off) x += o;
        }
        float T = __shfl(x, 63);
        s_dt[h][j] = dt;
        s_cum[h][j] = x;
        s_w[h][j] = __expf(T - x) * dt;
        EB[((size_t)(b * NC + c)) * 128 + h * 64 + j] = __expf(x);
        if (j == 0) TB[(b * 2 + h) * NC + c] = __expf(T);
    }

    // Phase B: conv(4)+bias+SiLU from global ZXb (width 384); scatter to MFMA layouts
    size_t cbbase = ((size_t)(b * NC + c)) * 8192;
    for (int e = tid; e < 64 * 96; e += 1024) {
        int j = e / 96;
        int q = e - j * 96;
        int cc = q * 4;
        int l = c * QC + j;
        const unsigned short* zp = ZXb + (rbase + j) * XW + cc;
        uint2 a0 = *(const uint2*)zp;
        uint2 a1 = make_uint2(0, 0), a2 = make_uint2(0, 0), a3 = make_uint2(0, 0);
        if (l >= 1) a1 = *(const uint2*)(zp - XW);
        if (l >= 2) a2 = *(const uint2*)(zp - 2 * XW);
        if (l >= 3) a3 = *(const uint2*)(zp - 3 * XW);
        float v[4];
#pragma unroll
        for (int u = 0; u < 4; u++) {
            unsigned int w0 = (u < 2) ? a0.x : a0.y;
            unsigned int w1 = (u < 2) ? a1.x : a1.y;
            unsigned int w2 = (u < 2) ? a2.x : a2.y;
            unsigned int w3 = (u < 2) ? a3.x : a3.y;
            int sh = (u & 1) * 16;
            float r0 = bf2f((unsigned short)(w0 >> sh));
            float r1 = bf2f((unsigned short)(w1 >> sh));
            float r2 = bf2f((unsigned short)(w2 >> sh));
            float r3 = bf2f((unsigned short)(w3 >> sh));
            float4 wv = *(const float4*)(CW + (cc + u) * 4);
            float tt = CB[cc + u] + wv.w * r0 + wv.z * r1 + wv.y * r2 + wv.x * r3;
            v[u] = tt / (1.f + __expf(-tt));
        }
        if (cc < 128) {
#pragma unroll
            for (int u = 0; u < 4; u++) sXt[cc + u][j] = f2bf(v[u]);
        } else if (cc < 256) {
            int s = cc - 128;
            unsigned int p0 = f2bf(v[0]) | ((unsigned int)f2bf(v[1]) << 16);
            unsigned int p1 = f2bf(v[2]) | ((unsigned int)f2bf(v[3]) << 16);
            *(uint2*)&uBC[0][j][s] = make_uint2(p0, p1);
#pragma unroll
            for (int u = 0; u < 4; u++) sBt[s + u][j] = f2bf(v[u]);
        } else {
            int s = cc - 256;
            unsigned int p0 = f2bf(v[0]) | ((unsigned int)f2bf(v[1]) << 16);
            unsigned int p1 = f2bf(v[2]) | ((unsigned int)f2bf(v[3]) << 16);
            *(uint2*)&uBC[1][j][s] = make_uint2(p0, p1);
            *(uint2*)(CBuf + cbbase + (size_t)j * 128 + s) = make_uint2(p0, p1);
        }
    }
    __syncthreads();

    // Phase C: G = C.B^T (16 tiles / 16 waves), stage in regs, overlay sM
    f32x4 gacc;
    {
        int it = wid >> 2, jt = wid & 3;
        f32x4 acc = {0.f, 0.f, 0.f, 0.f};
        for (int ks = 0; ks < 4; ks++) {
            bf16x8 a = fragld(&uBC[1][0][0], it * 16, ks * 32, 136);
            bf16x8 bb = fragld(&uBC[0][0][0], jt * 16, ks * 32, 136);
            acc = __builtin_amdgcn_mfma_f32_16x16x32_bf16(a, bb, acc, 0, 0, 0);
        }
        gacc = acc;
    }
    __syncthreads();
    {
        int it = wid >> 2, jt = wid & 3;
        int j = jt * 16 + c16;
        for (int rr = 0; rr < 4; rr++) {
            int i = it * 16 + q4 * 4 + rr;
            float gv = gacc[rr];
            for (int h = 0; h < 2; h++) {
                float m = 0.f;
                if (j <= i) m = gv * __expf(s_cum[h][i] - s_cum[h][j]) * s_dt[h][j];
                sM[h][i][j] = f2bf(m);
            }
        }
    }
    __syncthreads();

    // Phase D1: Y_intra = M_h @ X_h + D*x (32 tiles / 16 waves) — tile-major store
    size_t ybase = ((size_t)(b * NC + c)) * 8192;   // 32 tiles * 256 elems per chunk
#pragma unroll
    for (int u = 0; u < 2; u++) {
        int idx = wid * 2 + u;
        int h = idx >> 4, tt = idx & 15;
        int it = tt >> 2, pt = tt & 3;
        float dco = Dv[h];
        int pg = h * 64 + pt * 16 + c16;
        f32x4 acc;
        for (int rr = 0; rr < 4; rr++) {
            int i = it * 16 + q4 * 4 + rr;
            acc[rr] = dco * bf2f(sXt[pg][i]);
        }
        for (int ks = 0; ks < 2; ks++) {
            bf16x8 a = fragld(&sM[h][0][0], it * 16, ks * 32, 72);
            bf16x8 bb = fragld(&sXt[0][0], h * 64 + pt * 16, ks * 32, 72);
            acc = __builtin_amdgcn_mfma_f32_16x16x32_bf16(a, bb, acc, 0, 0, 0);
        }
        uint2 pk;
        pk.x = f2bf(acc[0]) | ((unsigned int)f2bf(acc[1]) << 16);
        pk.y = f2bf(acc[2]) | ((unsigned int)f2bf(acc[3]) << 16);
        *(uint2*)(YBb + ybase + (size_t)idx * 256 + lane * 4) = pk;
    }
    // Phase D2: SL^T[p][s] (64 tiles / 16 waves)
    size_t slbase = ((size_t)(b * NC + c)) * 16384;
#pragma unroll
    for (int u = 0; u < 4; u++) {
        int idx = wid * 4 + u;
        int ptl = idx >> 3, st = idx & 7;
        int h = ptl >> 2;
        f32x4 acc = {0.f, 0.f, 0.f, 0.f};
        for (int ks = 0; ks < 2; ks++) {
            int jb = ks * 32 + (lane >> 4) * 8;
            bf16x8 a = fragld(&sXt[0][0], ptl * 16, ks * 32, 72);
            bf16x8 aw;
#pragma unroll
            for (int t = 0; t < 8; t++) aw[t] = (short)f2bf(bf2f((unsigned short)a[t]) * s_w[h][jb + t]);
            bf16x8 bb = fragld(&sBt[0][0], st * 16, ks * 32, 72);
            acc = __builtin_amdgcn_mfma_f32_16x16x32_bf16(aw, bb, acc, 0, 0, 0);
        }
        int s = st * 16 + c16;
        for (int rr = 0; rr < 4; rr++) {
            int p = ptl * 16 + q4 * 4 + rr;
            float vv = acc[rr];
            float vn = __shfl_xor(vv, 1);
            if (!(lane & 1)) {
                unsigned int pk = f2bf(vv) | ((unsigned int)f2bf(vn) << 16);
                *(unsigned int*)(SL + slbase + (size_t)p * 128 + s) = pk;
            }
        }
    }
}

// ---------------- cross-chunk state scan (512 blk x 256 thr) ----------------
__global__ __launch_bounds__(256) void k_scan(unsigned short* __restrict__ SL,
                                              const float* __restrict__ TB) {
    int bid = blockIdx.x;
    int b = bid >> 6;
    int ps = (bid & 63) * 256 + threadIdx.x;
    int h = ps >> 13;
    const float* dAp = TB + (b * 2 + h) * NC;
    size_t base = (size_t)(b * NC) * 16384 + ps;
    float hacc = 0.f;
#pragma unroll 8
    for (int cc = 0; cc < NC; cc++) {
        size_t idx = base + (size_t)cc * 16384;
        float slv = bf2f(SL[idx]);
        SL[idx] = f2bf(hacc);
        hacc = hacc * dAp[cc] + slv;
    }
}

// ---------------- fused (1024 thr): z-GEMM + Y_inter + gate + RMSNorm + out_proj + residual
//                  + next-layer in_proj (row-local, from LDS) ----------------
__global__ __launch_bounds__(1024, 8) void k_fused(
        const unsigned short* __restrict__ SL, const unsigned short* __restrict__ CBuf,
        const float* __restrict__ EB,
        const unsigned short* __restrict__ YBb, const unsigned short* __restrict__ Wzb,
        const float* __restrict__ NW, const unsigned short* __restrict__ OWb,
        unsigned short* __restrict__ Xb, float* __restrict__ OutF,
        const unsigned short* __restrict__ WbN,      // next layer's in_proj weights (bf16)
        unsigned short* __restrict__ ZXbO,           // next layer's xBC buffer
        float* __restrict__ DTO,                     // next layer's dt buffer
        int last) {
    __shared__ __attribute__((aligned(16))) unsigned short sH[128][136];
    __shared__ __attribute__((aligned(16))) unsigned short sE[128][136];
    float* sGf = (float*)&sH[0][0];                                   // [64][132] overlay (dead after RMS)
    unsigned short (*sG)[136] = (unsigned short (*)[136])&sE[0][0];   // [64][136] overlay
    unsigned short (*sX2)[72] = (unsigned short (*)[72])&sH[0][0];    // [64][72] overlay (written in out_proj)

    int c = blockIdx.x, b = blockIdx.y;
    size_t rbase = (size_t)b * SEQ + c * QC;
    int tid = threadIdx.x;
    int wid = tid >> 6, lane = tid & 63;
    size_t base = ((size_t)(b * NC + c)) * 16384;
    for (int u = 0; u < 2; u++) {
        int e = u * 1024 + tid;
        int row = e >> 4, cb8 = (e & 15) * 8;
        *(uint4*)&sH[row][cb8] = *(const uint4*)(SL + base + (size_t)row * 128 + cb8);
    }
    size_t cbbase = ((size_t)(b * NC + c)) * 8192;
    size_t ebase  = ((size_t)(b * NC + c)) * 128;
    {
        int i = tid >> 4, sc = (tid & 15) * 8;
        uint4 cv = *(const uint4*)(CBuf + cbbase + (size_t)i * 128 + sc);
        float e0 = EB[ebase + i], e1 = EB[ebase + 64 + i];
        unsigned int w[4] = {cv.x, cv.y, cv.z, cv.w};
        uint4 o0, o1;
        unsigned int* po0 = &o0.x;
        unsigned int* po1 = &o1.x;
#pragma unroll
        for (int t = 0; t < 4; t++) {
            float lo = bf2f((unsigned short)(w[t] & 0xffff));
            float hi = bf2f((unsigned short)(w[t] >> 16));
            po0[t] = f2bf(lo * e0) | ((unsigned int)f2bf(hi * e0) << 16);
            po1[t] = f2bf(lo * e1) | ((unsigned int)f2bf(hi * e1) << 16);
        }
        *(uint4*)&sE[i][sc] = o0;
        *(uint4*)&sE[64 + i][sc] = o1;
    }
    __syncthreads();
    int q4 = lane >> 4, c16 = lane & 15;

    float yv[2][4];
    int tit[2], tpg[2];
    size_t ybase = ((size_t)(b * NC + c)) * 8192;
#pragma unroll
    for (int u = 0; u < 2; u++) {
        int idx = wid * 2 + u;                 // 32 tiles / 16 waves
        int h = idx >> 4, tt = idx & 15;
        int it = tt >> 2, pt = tt & 3;
        int pg = h * 64 + pt * 16 + c16;
        f32x4 zacc = {0.f, 0.f, 0.f, 0.f};
        f32x4 acc = {0.f, 0.f, 0.f, 0.f};
#pragma unroll
        for (int ks = 0; ks < 2; ks++) {
            bf16x8 xa = fragld(Xb, (int)rbase + it * 16, ks * 32, 64);
            bf16x8 wz = fragld(Wzb, h * 64 + pt * 16, ks * 32, 64);
            zacc = __builtin_amdgcn_mfma_f32_16x16x32_bf16(xa, wz, zacc, 0, 0, 0);
        }
        for (int ks = 0; ks < 4; ks++) {
            bf16x8 a = fragld(&sE[0][0], h * 64 + it * 16, ks * 32, 136);
            bf16x8 bb = fragld(&sH[0][0], h * 64 + pt * 16, ks * 32, 136);
            acc = __builtin_amdgcn_mfma_f32_16x16x32_bf16(a, bb, acc, 0, 0, 0);
        }
        tit[u] = it; tpg[u] = pg;
        uint2 yi = *(const uint2*)(YBb + ybase + (size_t)idx * 256 + lane * 4);
        float yin[4] = {bf2f((unsigned short)(yi.x & 0xffff)), bf2f((unsigned short)(yi.x >> 16)),
                        bf2f((unsigned short)(yi.y & 0xffff)), bf2f((unsigned short)(yi.y >> 16))};
        for (int rr = 0; rr < 4; rr++) {
            float y = acc[rr] + yin[rr];
            float z = zacc[rr];
            yv[u][rr] = y * (z / (1.f + __expf(-z)));
        }
    }
    __syncthreads();
#pragma unroll
    for (int u = 0; u < 2; u++)
        for (int rr = 0; rr < 4; rr++) {
            int i = tit[u] * 16 + q4 * 4 + rr;
            sGf[i * 132 + tpg[u]] = yv[u][rr];
        }
    __syncthreads();
    {
        int row = tid >> 4, part = tid & 15;
        int d0 = part * 8;
        float g[8];
        float ss = 0.f;
        for (int t2 = 0; t2 < 8; t2++) { g[t2] = sGf[row * 132 + d0 + t2]; ss += g[t2] * g[t2]; }
        ss += __shfl_xor(ss, 1);
        ss += __shfl_xor(ss, 2);
        ss += __shfl_xor(ss, 4);
        ss += __shfl_xor(ss, 8);
        float rms = rsqrtf(ss * (1.f / 128.f) + 1e-5f);
        for (int t2 = 0; t2 < 8; t2 += 2) {
            unsigned int pk = f2bf(g[t2] * rms * NW[d0 + t2]) |
                              ((unsigned int)f2bf(g[t2 + 1] * rms * NW[d0 + t2 + 1]) << 16);
            *(unsigned int*)&sG[row][d0 + t2] = pk;
        }
    }
    __syncthreads();
    {
        // out_proj: 16 tiles over 16 waves (mt 0..3 × nt 0..3); also stage new-x into sX2
        int mt = wid >> 2, nt = wid & 3;
        f32x4 acc = {0.f, 0.f, 0.f, 0.f};
        for (int ks = 0; ks < 4; ks++) {
            bf16x8 a = fragld(&sG[0][0], mt * 16, ks * 32, 136);
            bf16x8 bb = *(const bf16x8*)(OWb + (size_t)(nt * 16 + c16) * 128 + ks * 32 + q4 * 8);
            acc = __builtin_amdgcn_mfma_f32_16x16x32_bf16(a, bb, acc, 0, 0, 0);
        }
        for (int rr = 0; rr < 4; rr++) {
            int m = mt * 16 + q4 * 4 + rr;
            int n = nt * 16 + c16;
            size_t o = (rbase + m) * DM + n;
            float v = bf2f(Xb[o]) + acc[rr];
            if (last) {
                OutF[o] = v;
            } else {
                unsigned short vb = f2bf(v);
                sX2[m][n] = vb;
                float vn = __shfl_xor(v, 1);
                if (!(lane & 1)) {
                    unsigned int pk = (unsigned int)vb | ((unsigned int)f2bf(vn) << 16);
                    *(unsigned int*)(Xb + o) = pk;
                }
            }
        }
    }
    if (!last) {
        __syncthreads();
        // next-layer in_proj for rows rbase..rbase+63: 100 tile jobs over 16 waves
        for (int t = wid; t < 100; t += 16) {
            int mt2, n0;
            int isdt = (t >= 96);
            if (!isdt) { mt2 = t & 3; n0 = (t >> 2) * 16; }
            else       { mt2 = t - 96; n0 = 0; }
            bf16x8 a0 = fragld(&sX2[0][0], mt2 * 16, 0, 72);
            bf16x8 a1 = fragld(&sX2[0][0], mt2 * 16, 32, 72);
            const unsigned short* wrow = isdt ? (WbN + (size_t)(512 + c16) * 64)
                                              : (WbN + (size_t)(128 + n0 + c16) * 64);
            bf16x8 b0 = *(const bf16x8*)(wrow + q4 * 8);
            bf16x8 b1 = *(const bf16x8*)(wrow + 32 + q4 * 8);
            f32x4 acc = {0.f, 0.f, 0.f, 0.f};
            acc = __builtin_amdgcn_mfma_f32_16x16x32_bf16(a0, b0, acc, 0, 0, 0);
            acc = __builtin_amdgcn_mfma_f32_16x16x32_bf16(a1, b1, acc, 0, 0, 0);
            if (!isdt) {
#pragma unroll
                for (int rr = 0; rr < 4; rr++) {
                    float v = acc[rr];
                    float vn = __shfl_xor(v, 1);
                    if (!(lane & 1)) {
                        unsigned int pk = f2bf(v) | ((unsigned int)f2bf(vn) << 16);
                        *(unsigned int*)(ZXbO + (rbase + mt2 * 16 + q4 * 4 + rr) * XW + n0 + c16) = pk;
                    }
                }
            } else {
                if (c16 < 2)
#pragma unroll
                    for (int rr = 0; rr < 4; rr++)
                        DTO[(rbase + mt2 * 16 + q4 * 4 + rr) * 2 + c16] = acc[rr];
            }
        }
    }
}

extern "C" void kernel_launch(void* const* d_in, const int* in_sizes, int n_in,
                              void* d_out, int out_size, void* d_ws, size_t ws_size,
                              hipStream_t stream) {
    const float* x       = (const float*)d_in[0];
    const float* in_w    = (const float*)d_in[1];
    const float* conv_w  = (const float*)d_in[2];
    const float* conv_b  = (const float*)d_in[3];
    const float* dt_bias = (const float*)d_in[4];
    const float* A_log   = (const float*)d_in[5];
    const float* Dp      = (const float*)d_in[6];
    const float* norm_w  = (const float*)d_in[7];
    const float* out_w   = (const float*)d_in[8];
    float* out = (float*)d_out;
    float* ws  = (float*)d_ws;

    float* dt = ws;                                        // NR*2 f32
    float* tb = dt + (size_t)NR * 2;                       // 1024 f32
    float* eb = tb + 1024;                                 // 8*64*128 f32
    unsigned short* zxb  = (unsigned short*)(eb + (size_t)B_SZ * NC * 128); // NR*384
    unsigned short* ybb  = zxb + (size_t)NR * XW;          // 8*64*8192 (tile-major)
    unsigned short* sl   = ybb + (size_t)B_SZ * NC * 8192; // 8*64*16384
    unsigned short* cbuf = sl + (size_t)B_SZ * NC * 16384; // 8*64*8192
    unsigned short* xb   = cbuf + (size_t)B_SZ * NC * 8192;// NR*64
    unsigned short* wb   = xb + (size_t)NR * DM;           // 4*576*64
    unsigned short* owb  = wb + (size_t)4 * WPAD * 64;     // 4*64*128

    k_wcvt<<<(4 * WPAD * 64 + 255) / 256, 256, 0, stream>>>(in_w, out_w, wb, owb);
    k_xcvt<<<NR * DM / 1024, 256, 0, stream>>>(x, xb);
    k_inproj<<<dim3(NR / 256, 7), 256, 0, stream>>>(xb, wb, zxb, dt);   // layer 0 only

    for (int layer = 0; layer < 4; layer++) {
        int nl = (layer < 3) ? layer + 1 : 3;
        k_chunk1<<<dim3(NC, B_SZ), 1024, 0, stream>>>(zxb, dt,
                conv_w + (size_t)layer * CD * 4, conv_b + (size_t)layer * CD,
                dt_bias + layer * NH, A_log + layer * NH, Dp + layer * NH,
                sl, cbuf, eb, tb, ybb);
        k_scan<<<512, 256, 0, stream>>>(sl, tb);
        k_fused<<<dim3(NC, B_SZ), 1024, 0, stream>>>(sl, cbuf, eb, ybb,
                wb + (size_t)layer * WPAD * 64, norm_w + layer * DI,
                owb + (size_t)layer * 64 * 128, xb, out,
                wb + (size_t)nl * WPAD * 64, zxb, dt,
                (layer == 3) ? 1 : 0);
    }
}